// Round 17
// baseline (240.511 us; speedup 1.0000x reference)
//
#include <hip/hip_runtime.h>
#include <hip/hip_bf16.h>

typedef unsigned short u16;
typedef unsigned int u32;
typedef __attribute__((ext_vector_type(8))) unsigned short us8;
typedef __attribute__((ext_vector_type(4))) unsigned short us4;
typedef __attribute__((ext_vector_type(2))) unsigned int u32x2;
typedef __attribute__((ext_vector_type(8))) short bf16x8;   // 8 bf16 in 4 VGPRs
typedef __attribute__((ext_vector_type(4))) float f32x4;

#define QSCALE 0.18033688011112042f   // 0.125 * log2(e): folded into Q epilogue

__device__ __forceinline__ u16 f2bf(float f) {
    __hip_bfloat16 h = __float2bfloat16(f);   // RNE
    return __builtin_bit_cast(u16, h);
}
// pack two floats to bf16 pair in one instr (lo in [15:0], hi in [31:16])
__device__ __forceinline__ u32 cvtpk(float lo, float hi) {
    u32 r;
    asm("v_cvt_pk_bf16_f32 %0, %1, %2" : "=v"(r) : "v"(lo), "v"(hi));
    return r;
}
// raw v_exp_f32 (no libm range-guard code); fine for |x| < 126
__device__ __forceinline__ float ex2(float x) {
    return __builtin_amdgcn_exp2f(x);
}
// tanh-form GELU, 7 VALU ops, inf-safe at both tails (max err ~3e-4)
__device__ __forceinline__ float gelu7(float v) {
    const float a = v * fmaf(0.10294324f, v * v, 2.3022082f);
    const float E = ex2(a);
    return v - v * __builtin_amdgcn_rcpf(1.0f + E);
}
// async global(16B/lane) -> LDS (wave-uniform base + lane*16)
__device__ __forceinline__ void gll16(const u16* g, u16* l) {
    __builtin_amdgcn_global_load_lds(
        (const __attribute__((address_space(1))) unsigned int*)g,
        (__attribute__((address_space(3))) unsigned int*)l, 16, 0, 0);
}
template<int N> __device__ __forceinline__ void waitv() {
    if constexpr (N == 0)       asm volatile("s_waitcnt vmcnt(0)" ::: "memory");
    else if constexpr (N == 4)  asm volatile("s_waitcnt vmcnt(4)" ::: "memory");
    else if constexpr (N == 6)  asm volatile("s_waitcnt vmcnt(6)" ::: "memory");
    else if constexpr (N == 8)  asm volatile("s_waitcnt vmcnt(8)" ::: "memory");
    else static_assert(N == 0, "unsupported vmcnt");
}

// ---------------------------------------------------------------------------
// fp32 [KK][NN] -> bf16 transposed [NN][KK]
// ---------------------------------------------------------------------------
__global__ void tcvt_k(const float* __restrict__ W, u16* __restrict__ Wt, int KK, int NN)
{
    __shared__ float tile[32][33];
    const int n0 = blockIdx.x * 32, k0 = blockIdx.y * 32;
    const int tx = threadIdx.x, ty = threadIdx.y;
    #pragma unroll
    for (int j = ty; j < 32; j += 8)
        tile[j][tx] = W[(size_t)(k0 + j) * NN + n0 + tx];
    __syncthreads();
    #pragma unroll
    for (int j = ty; j < 32; j += 8)
        Wt[(size_t)(n0 + j) * KK + k0 + tx] = f2bf(tile[tx][j]);
}

// four 1024x1024 transposes in one launch (z selects weight; outputs contiguous)
__global__ void tcvt4_k(const float* __restrict__ a, const float* __restrict__ b,
                        const float* __restrict__ c, const float* __restrict__ d,
                        u16* __restrict__ out)
{
    __shared__ float tile[32][33];
    const int z = blockIdx.z;
    const float* W = (z == 0) ? a : (z == 1) ? b : (z == 2) ? c : d;
    u16* Wt = out + (size_t)z * 1024 * 1024;
    const int n0 = blockIdx.x * 32, k0 = blockIdx.y * 32;
    const int tx = threadIdx.x, ty = threadIdx.y;
    #pragma unroll
    for (int j = ty; j < 32; j += 8)
        tile[j][tx] = W[(size_t)(k0 + j) * 1024 + n0 + tx];
    __syncthreads();
    #pragma unroll
    for (int j = ty; j < 32; j += 8)
        Wt[(size_t)(n0 + j) * 1024 + k0 + tx] = f2bf(tile[tx][j]);
}

// ---------------------------------------------------------------------------
// bf16 [32][2048][64] -> [32][64][2048]  (V transpose for PV B-operand reads)
// ---------------------------------------------------------------------------
__global__ __launch_bounds__(256) void vtr_k(const u16* __restrict__ Vb, u16* __restrict__ Vt)
{
    __shared__ u16 t[64][72];
    const int bh = blockIdx.y, s0 = blockIdx.x * 64;
    const int tid = threadIdx.x;
    const size_t ibase = (size_t)bh * 2048 * 64 + (size_t)s0 * 64;
    #pragma unroll
    for (int c = tid; c < 512; c += 256) {
        const us8 v = *(const us8*)(Vb + ibase + (size_t)(c >> 3) * 64 + (c & 7) * 8);
        *(us8*)(&t[c >> 3][(c & 7) * 8]) = v;
    }
    __syncthreads();
    const size_t obase = (size_t)bh * 64 * 2048 + s0;
    #pragma unroll
    for (int c = tid; c < 512; c += 256) {
        const int hd = c >> 3, sl0 = (c & 7) * 8;
        us8 v;
        #pragma unroll
        for (int j = 0; j < 8; j++) v[j] = t[sl0 + j][hd];
        *(us8*)(Vt + obase + (size_t)hd * 2048 + sl0) = v;
    }
}

// ---------------------------------------------------------------------------
// LayerNorm (D=1024): wave-per-row, 4 rows per block (grid 1024).
// Wave-local shfl_xor reduction only -- no LDS, no barrier.
// ---------------------------------------------------------------------------
__global__ __launch_bounds__(256) void ln_k(const float* __restrict__ x,
                                            const float* __restrict__ g,
                                            const float* __restrict__ b,
                                            u16* __restrict__ h)
{
    const int l = threadIdx.x & 63, w = threadIdx.x >> 6;
    const int row = blockIdx.x * 4 + w;
    const float* xr = x + (size_t)row * 1024;
    float4 v[4];
    float sum = 0.0f, sq = 0.0f;
    #pragma unroll
    for (int i = 0; i < 4; i++) {
        v[i] = *(const float4*)(xr + i * 256 + l * 4);
        sum += (v[i].x + v[i].y) + (v[i].z + v[i].w);
        sq  += (v[i].x * v[i].x + v[i].y * v[i].y)
             + (v[i].z * v[i].z + v[i].w * v[i].w);
    }
    #pragma unroll
    for (int off = 32; off >= 1; off >>= 1) {
        sum += __shfl_xor(sum, off);
        sq  += __shfl_xor(sq, off);
    }
    const float mean = sum * (1.0f / 1024.0f);
    const float var  = sq * (1.0f / 1024.0f) - mean * mean;
    const float inv  = rsqrtf(var + 1e-6f);
    u16* hr = h + (size_t)row * 1024;
    #pragma unroll
    for (int i = 0; i < 4; i++) {
        const int c = i * 256 + l * 4;
        us4 o;
        o[0] = f2bf((v[i].x - mean) * inv * g[c + 0] + b[c + 0]);
        o[1] = f2bf((v[i].y - mean) * inv * g[c + 1] + b[c + 1]);
        o[2] = f2bf((v[i].z - mean) * inv * g[c + 2] + b[c + 2]);
        o[3] = f2bf((v[i].w - mean) * inv * g[c + 3] + b[c + 3]);
        *(us4*)(hr + c) = o;
    }
}

// ---------------------------------------------------------------------------
// Pipelined MFMA GEMM body: C[M,N] = A[M,K] @ Bt[N,K]^T (R11/R16 form).
// TM x 128 tile, BK in {32,64}, double-buffered LDS, gll16 staging.
// Per K-step: barrier; stage(next); vmcnt(NI); barrier; ds_read+MFMA.
// LDS dest LINEAR; global SOURCE col-block inverse-swizzled; reads swizzled
// (rule #21). BK=32: 4-blk swizzle ^((lr>>1)&3); BK=64: 8-blk ^(lr&7).
// EPI: 0 = bias, *scale, bf16 scatter to [B*H][S][HD]
//      1/3 = bias + addsrc(f32) residual -> f32 out (stride 1024)
//      2 = bias + tanh-form GELU (gelu7) -> bf16 out (stride 4096)
// ---------------------------------------------------------------------------
template<int EPI, int TM, int BK>
__device__ __forceinline__ void gemm_body(const u16* __restrict__ A,
                                          const u16* __restrict__ Bt,
                                          const float* __restrict__ bias,
                                          void* __restrict__ outp,
                                          const float* __restrict__ addsrc,
                                          int K, float scale, int m0, int n0)
{
    constexpr int MI  = TM / 32;
    constexpr int ASZ = TM * BK;
    constexpr int BSZ = 128 * BK;
    constexpr int RPI = 512 / BK;
    constexpr int NIA = (TM / 4) / RPI;
    constexpr int NIB = 32 / RPI;
    constexpr int NI  = NIA + NIB;
    __shared__ u16 As[2 * ASZ];
    __shared__ u16 Bs[2 * BSZ];
    const int tid = threadIdx.x;
    const int l = tid & 63, w = tid >> 6;
    const int wr = w >> 1, wc = w & 1;
    const int lr = l & 15, lg = l >> 4;

    int srow, sblk;
    if constexpr (BK == 32) { srow = l >> 2; sblk = (l & 3) ^ ((l >> 3) & 3); }
    else                    { srow = l >> 3; sblk = (l & 7) ^ (l >> 3); }
    const u16* gA = A  + (size_t)(m0 + w * (TM / 4) + srow) * K + sblk * 8;
    const u16* gB = Bt + (size_t)(n0 + w * 32 + srow) * K + sblk * 8;
    const size_t rowKi = (size_t)RPI * K;
    u16* const lA0 = As + w * (TM / 4) * BK;
    u16* const lB0 = Bs + w * 32 * BK;

    f32x4 acc[MI][4];
    #pragma unroll
    for (int i = 0; i < MI; i++)
        #pragma unroll
        for (int j = 0; j < 4; j++) acc[i][j] = (f32x4)(0.0f);

    auto stage = [&](int buf, int kb) {
        u16* la = lA0 + buf * ASZ;
        u16* lb = lB0 + buf * BSZ;
        #pragma unroll
        for (int i = 0; i < NIA; i++) gll16(gA + kb + i * rowKi, la + i * 512);
        #pragma unroll
        for (int i = 0; i < NIB; i++) gll16(gB + kb + i * rowKi, lb + i * 512);
    };

    const int nK = K / BK;
    stage(0, 0);
    int cur = 0;
    for (int kt = 0; kt < nK; ++kt) {
        __builtin_amdgcn_sched_barrier(0);
        __builtin_amdgcn_s_barrier();
        __builtin_amdgcn_sched_barrier(0);
        if (kt + 1 < nK) {
            stage(cur ^ 1, (kt + 1) * BK);
            waitv<NI>();
        } else {
            waitv<0>();
        }
        __builtin_amdgcn_s_barrier();
        __builtin_amdgcn_sched_barrier(0);

        const u16* as = As + cur * ASZ;
        const u16* bs = Bs + cur * BSZ;
        #pragma unroll
        for (int ks = 0; ks < BK / 32; ks++) {
            int off;
            if constexpr (BK == 32) off = (lg ^ ((lr >> 1) & 3)) * 8;
            else                    off = ((ks * 4 + lg) ^ (lr & 7)) * 8;
            bf16x8 af[MI], bf[4];
            #pragma unroll
            for (int mi = 0; mi < MI; mi++)
                af[mi] = *(const bf16x8*)(as + (wr * (MI * 16) + mi * 16 + lr) * BK + off);
            #pragma unroll
            for (int ni = 0; ni < 4; ni++)
                bf[ni] = *(const bf16x8*)(bs + (wc * 64 + ni * 16 + lr) * BK + off);
            #pragma unroll
            for (int mi = 0; mi < MI; mi++)
                #pragma unroll
                for (int ni = 0; ni < 4; ni++)
                    acc[mi][ni] = __builtin_amdgcn_mfma_f32_16x16x32_bf16(
                        af[mi], bf[ni], acc[mi][ni], 0, 0, 0);
        }
        cur ^= 1;
    }

    const int r0 = lg * 4;
    #pragma unroll
    for (int mi = 0; mi < MI; mi++) {
        #pragma unroll
        for (int ni = 0; ni < 4; ni++) {
            const int col = n0 + wc * 64 + ni * 16 + lr;
            const float bv = bias[col];
            #pragma unroll
            for (int r = 0; r < 4; r++) {
                const int row = m0 + wr * (MI * 16) + mi * 16 + r0 + r;
                const float v = acc[mi][ni][r] + bv;
                if constexpr (EPI == 0) {
                    const int bb = row >> 11, s = row & 2047;
                    const int hh = col >> 6, hd = col & 63;
                    ((u16*)outp)[(((size_t)(bb * 16 + hh) * 2048) + s) * 64 + hd] = f2bf(v * scale);
                } else if constexpr (EPI == 1 || EPI == 3) {
                    const size_t idx = (size_t)row * 1024 + col;
                    ((float*)outp)[idx] = addsrc[idx] + v;
                } else {
                    ((u16*)outp)[(size_t)row * 4096 + col] = f2bf(gelu7(v));
                }
            }
        }
    }
}

// 1-D grid, bijective XCD swizzle (nwg % 8 == 0), n-fast within an XCD.
template<int EPI, int TM, int BK, int NX>
__global__ __launch_bounds__(256) void gemm_k(const u16* __restrict__ A,
                                              const u16* __restrict__ Bt,
                                              const float* __restrict__ bias,
                                              void* __restrict__ outp,
                                              const float* __restrict__ addsrc,
                                              int K)
{
    const int nwg = gridDim.x;
    const int s = (blockIdx.x & 7) * (nwg >> 3) + (blockIdx.x >> 3);
    gemm_body<EPI, TM, BK>(A, Bt, bias, outp, addsrc, K, 1.0f,
                           (s / NX) * TM, (s % NX) * 128);
}

// MLP2 (M=4096/TM=64, N=1024 -> 8 n-panels, K=4096), grid 512.
// n-PINNED mapping: XCD x owns n-panel x (1MB B, L2-resident for the whole
// kernel) and walks all 64 m-tiles m-fast. A (33.5MB) becomes L3-resident;
// all XCDs stream it in the same order. B: L2 hits; A: L3 hits covered by
// the 1-step prefetch. Fetch bound ~= unique bytes (41.5MB, was 57.4).
__global__ __launch_bounds__(256) void gemm_mlp2_k(const u16* __restrict__ A,
                                                   const u16* __restrict__ Bt,
                                                   const float* __restrict__ bias,
                                                   void* __restrict__ outp,
                                                   const float* __restrict__ addsrc,
                                                   int K)
{
    const int n = blockIdx.x & 7;             // XCD-pinned n-panel
    const int m = blockIdx.x >> 3;            // 0..63, m-fast
    gemm_body<3, 64, 64>(A, Bt, bias, outp, addsrc, K, 1.0f, m * 64, n * 128);
}

// MLP1 (TM=64/BK=64, grid 2048): XCD owns 16m x 16n super-tile, walked in
// 4 generations of 16m x 4n (m-fast inner); generation working set ~3MB.
__global__ __launch_bounds__(256) void gemm_mlp1_k(const u16* __restrict__ A,
                                                   const u16* __restrict__ Bt,
                                                   const float* __restrict__ bias,
                                                   void* __restrict__ outp,
                                                   int K)
{
    const int x = blockIdx.x & 7;
    const int idx = blockIdx.x >> 3;          // 0..255
    const int m = (x >> 1) * 16 + (idx & 15);
    const int n = (x & 1) * 16 + (idx >> 6) * 4 + ((idx >> 4) & 3);
    gemm_body<2, 64, 64>(A, Bt, bias, outp, nullptr, K, 1.0f, m * 64, n * 128);
}

// fused QKV (grid 768): XCD owns a disjoint 4-m-panel slice of shared A.
__global__ __launch_bounds__(256) void gemm_qkv_k(const u16* __restrict__ A,
                                                  const u16* __restrict__ WtBase,
                                                  const float* __restrict__ bq,
                                                  const float* __restrict__ bk,
                                                  const float* __restrict__ bv,
                                                  u16* __restrict__ outBase)
{
    const int x = blockIdx.x & 7;
    const int i = blockIdx.x >> 3;            // 0..95
    const int m = x * 4 + (i & 3);            // 0..31
    const int rest = i >> 2;                  // 0..23
    const int z = rest >> 3, n = rest & 7;
    const u16* Bt = WtBase + (size_t)z * 1024 * 1024;
    const float* bias = (z == 0) ? bq : (z == 1) ? bk : bv;
    u16* outp = outBase + (size_t)z * 4096 * 1024;
    const float scale = (z == 0) ? QSCALE : 1.0f;
    gemm_body<0, 128, 32>(A, Bt, bias, outp, nullptr, 1024, scale,
                          m * 128, n * 128);
}

// ---------------------------------------------------------------------------
// MFMA flash attention, swapped-QK^T, no max tracking; KV-TILE = 128 (R16):
// one barrier pair + one counted vmcnt per 128 kv (two 64-kv compute passes
// inside). Wave owns 32 q rows as two 16-row groups sharing every K/V
// fragment read. Grid 512 (2 blocks/CU, LDS 80KB).
// ---------------------------------------------------------------------------
__global__ __launch_bounds__(256) void attn_mfma_k(
    const u16* __restrict__ Qb, const u16* __restrict__ Kb,
    const u16* __restrict__ Vt, u16* __restrict__ Oo)
{
    __shared__ u16 Kl[2][128 * 64];    // [kv][hd]
    __shared__ u16 Vl[2][64 * 128];    // [hd][kv]
    __shared__ u16 Pl[4][32 * 64];     // per-wave P: 32 q rows

    const int tid = threadIdx.x;
    const int l = tid & 63, w = tid >> 6;
    const int lr = l & 15, lg = l >> 4;
    const int bid = blockIdx.x;
    const int bh = (bid & 7) * 4 + ((bid >> 3) >> 4);   // 4 heads per XCD
    const int qblk = (bid >> 3) & 15;
    const size_t base = (size_t)bh * 2048 * 64;
    const size_t vbase = (size_t)bh * 64 * 2048;
    const int q0 = qblk * 128 + w * 32;

    bf16x8 qf[2][2];
    #pragma unroll
    for (int g = 0; g < 2; g++)
        #pragma unroll
        for (int ks = 0; ks < 2; ks++)
            qf[g][ks] = *(const bf16x8*)(Qb + base + (size_t)(q0 + g * 16 + lr) * 64
                                         + ks * 32 + lg * 8);

    bf16x8 onef;
    #pragma unroll
    for (int j = 0; j < 8; j++) onef[j] = (short)0x3F80;

    f32x4 o_[2][4];
    f32x4 ol[2];
    #pragma unroll
    for (int g = 0; g < 2; g++) {
        #pragma unroll
        for (int r = 0; r < 4; r++) ol[g][r] = 0.0f;
        #pragma unroll
        for (int ni = 0; ni < 4; ni++) o_[g][ni] = (f32x4)(0.0f);
    }

    u16* const plw = &Pl[w][0];
    u16* pw_[2][4];
    const u16* pr_[2][2];
    #pragma unroll
    for (int g = 0; g < 2; g++) {
        #pragma unroll
        for (int ni = 0; ni < 4; ni++)
            pw_[g][ni] = plw + (g * 16 + lr) * 64
                       + (((ni * 2 + (lg >> 1)) ^ (lr & 7)) * 8 + (lg & 1) * 4);
        pr_[g][0] = plw + (g * 16 + lr) * 64 + ((lg ^ (lr & 7)) * 8);
        pr_[g][1] = plw + (g * 16 + lr) * 64 + (((4 + lg) ^ (lr & 7)) * 8);
    }

    const u16* gK = Kb + base + (size_t)(w * 32 + (l >> 3)) * 64
                  + (((l & 7) ^ (l >> 3)) * 8);
    u16* const kd = &Kl[0][0] + w * 32 * 64;

    const u16* gVsrc[4];
    #pragma unroll
    for (int i = 0; i < 4; i++) {
        const int vrow = w * 16 + i * 4 + (l >> 4);
        gVsrc[i] = Vt + vbase + (size_t)vrow * 2048
                 + (((l & 15) ^ (i * 4 + (l >> 4))) * 8);
    }
    u16* const vd = &Vl[0][0] + w * 16 * 128;

    auto stageT = [&](int buf, int kv) {
        u16* kdb = kd + buf * 8192;
        u16* vdb = vd + buf * 8192;
        #pragma unroll
        for (int i = 0; i < 4; i++)
            gll16(gK + (size_t)kv * 64 + i * 512, kdb + i * 512);
        #pragma unroll
        for (int i = 0; i < 4; i++)
            gll16(gVsrc[i] + kv, vdb + i * 512);
    };

    stageT(0, 0);
    int cur = 0;
    for (int t = 0; t < 16; ++t) {
        __builtin_amdgcn_sched_barrier(0);
        __builtin_amdgcn_s_barrier();
        __builtin_amdgcn_sched_barrier(0);
        if (t < 15) {
            stageT(cur ^ 1, (t + 1) * 128);
            waitv<8>();
        } else {
            waitv<0>();
        }
        __builtin_amdgcn_s_barrier();
        __builtin_amdgcn_sched_barrier(0);

        #pragma unroll
        for (int s = 0; s < 2; s++) {
            f32x4 s_[2][4];
            #pragma unroll
            for (int g = 0; g < 2; g++)
                #pragma unroll
                for (int ni = 0; ni < 4; ni++) s_[g][ni] = (f32x4)(0.0f);
            __builtin_amdgcn_s_setprio(1);
            #pragma unroll
            for (int ks = 0; ks < 2; ks++)
                #pragma unroll
                for (int ni = 0; ni < 4; ni++) {
                    const int row = ni * 16 + lr;
                    const bf16x8 kf = *(const bf16x8*)(
                        &Kl[cur][(s * 64 + row) * 64 + (((ks * 4 + lg) ^ (row & 7)) * 8)]);
                    s_[0][ni] = __builtin_amdgcn_mfma_f32_16x16x32_bf16(kf, qf[0][ks], s_[0][ni], 0, 0, 0);
                    s_[1][ni] = __builtin_amdgcn_mfma_f32_16x16x32_bf16(kf, qf[1][ks], s_[1][ni], 0, 0, 0);
                }
            __builtin_amdgcn_s_setprio(0);

            #pragma unroll
            for (int g = 0; g < 2; g++)
                #pragma unroll
                for (int ni = 0; ni < 4; ni++) {
                    u32x2 pv;
                    pv[0] = cvtpk(ex2(s_[g][ni][0]), ex2(s_[g][ni][1]));
                    pv[1] = cvtpk(ex2(s_[g][ni][2]), ex2(s_[g][ni][3]));
                    *(u32x2*)pw_[g][ni] = pv;
                }

            __builtin_amdgcn_s_setprio(1);
            #pragma unroll
            for (int ks = 0; ks < 2; ks++) {
                const bf16x8 pf0 = *(const bf16x8*)pr_[0][ks];
                const bf16x8 pf1 = *(const bf16x8*)pr_[1][ks];
                ol[0] = __builtin_amdgcn_mfma_f32_16x16x32_bf16(pf0, onef, ol[0], 0, 0, 0);
                ol[1] = __builtin_amdgcn_mfma_f32_16x16x32_bf16(pf1, onef, ol[1], 0, 0, 0);
                #pragma unroll
                for (int ni = 0; ni < 4; ni++) {
                    const int row = ni * 16 + lr;
                    const int chunk = s * 8 + ks * 4 + lg;
                    const bf16x8 vf = *(const bf16x8*)(
                        &Vl[cur][row * 128 + ((chunk ^ (row & 15)) * 8)]);
                    o_[0][ni] = __builtin_amdgcn_mfma_f32_16x16x32_bf16(pf0, vf, o_[0][ni], 0, 0, 0);
                    o_[1][ni] = __builtin_amdgcn_mfma_f32_16x16x32_bf16(pf1, vf, o_[1][ni], 0, 0, 0);
                }
            }
            __builtin_amdgcn_s_setprio(0);
        }
        cur ^= 1;
    }

    const int bb = bh >> 4, hh = bh & 15;
    #pragma unroll
    for (int g = 0; g < 2; g++)
        #pragma unroll
        for (int r = 0; r < 4; r++) {
            const float inv = 1.0f / ol[g][r];
            const int qrow = q0 + g * 16 + lg * 4 + r;
            u16* dst = Oo + ((size_t)(bb * 2048 + qrow)) * 1024 + hh * 64;
            #pragma unroll
            for (int ni = 0; ni < 4; ni++)
                dst[ni * 16 + lr] = f2bf(o_[g][ni][r] * inv);
        }
}

// ---------------------------------------------------------------------------
extern "C" void kernel_launch(void* const* d_in, const int* in_sizes, int n_in,
                              void* d_out, int out_size, void* d_ws, size_t ws_size,
                              hipStream_t stream)
{
    const float* x     = (const float*)d_in[0];
    const float* ln1_g = (const float*)d_in[1];
    const float* ln1_b = (const float*)d_in[2];
    const float* wq    = (const float*)d_in[3];
    const float* bq    = (const float*)d_in[4];
    const float* wk    = (const float*)d_in[5];
    const float* bk    = (const float*)d_in[6];
    const float* wv    = (const float*)d_in[7];
    const float* bv    = (const float*)d_in[8];
    const float* wo    = (const float*)d_in[9];
    const float* bo    = (const float*)d_in[10];
    const float* ln2_g = (const float*)d_in[11];
    const float* ln2_b = (const float*)d_in[12];
    const float* w1    = (const float*)d_in[13];
    const float* b1    = (const float*)d_in[14];
    const float* w2    = (const float*)d_in[15];
    const float* b2    = (const float*)d_in[16];

    char* ws = (char*)d_ws;
    size_t off = 0;
    auto alloc = [&](size_t bytes) {
        char* p = ws + off;
        off += (bytes + 255) & ~(size_t)255;
        return p;
    };
    // NOTE: wtq/wtk/wtv/wto must stay contiguous (tcvt4_k / gemm_qkv_k index
    // by z), as must qb/kb/vb. Each is an exact multiple of 256B.
    u16* wtq = (u16*)alloc((size_t)1024 * 1024 * 2);
    u16* wtk = (u16*)alloc((size_t)1024 * 1024 * 2);
    u16* wtv = (u16*)alloc((size_t)1024 * 1024 * 2);
    u16* wto = (u16*)alloc((size_t)1024 * 1024 * 2);
    u16* wt1 = (u16*)alloc((size_t)4096 * 1024 * 2);  // [MLP][D]
    u16* wt2 = (u16*)alloc((size_t)1024 * 4096 * 2);  // [D][MLP]
    u16* h1  = (u16*)alloc((size_t)4096 * 1024 * 2);
    u16* qb  = (u16*)alloc((size_t)4096 * 1024 * 2);  // [B*H][S][HD]
    u16* kb  = (u16*)alloc((size_t)4096 * 1024 * 2);
    u16* vb  = (u16*)alloc((size_t)4096 * 1024 * 2);
    u16* ao  = (u16*)alloc((size_t)4096 * 1024 * 2);  // [B,S,D]
    float* x2 = (float*)alloc((size_t)4096 * 1024 * 4);
    u16* h2  = (u16*)alloc((size_t)4096 * 1024 * 2);
    u16* mid = (u16*)alloc((size_t)4096 * 4096 * 2);
    // V^T [32][64][2048] aliases `mid` (mid is first written AFTER attention).
    u16* vt  = mid;
    (void)ws_size;
    (void)wtk; (void)wtv;

    const dim3 tb(32, 8);
    tcvt4_k<<<dim3(32, 32, 4), tb, 0, stream>>>(wq, wk, wv, wo, wtq);
    tcvt_k<<<dim3(128, 32), tb, 0, stream>>>(w1, wt1, 1024, 4096);
    tcvt_k<<<dim3(32, 128), tb, 0, stream>>>(w2, wt2, 4096, 1024);

    ln_k<<<1024, 256, 0, stream>>>(x, ln1_g, ln1_b, h1);

    gemm_qkv_k<<<768, 256, 0, stream>>>(h1, wtq, bq, bk, bv, qb);

    vtr_k<<<dim3(32, 32), 256, 0, stream>>>(vb, vt);
    attn_mfma_k<<<512, 256, 0, stream>>>(qb, kb, vt, ao);

    gemm_k<1, 64, 64, 8><<<512, 256, 0, stream>>>(ao, wto, bo, x2, x, 1024);

    ln_k<<<1024, 256, 0, stream>>>(x2, ln2_g, ln2_b, h2);

    gemm_mlp1_k<<<2048, 256, 0, stream>>>(h2, wt1, b1, mid, 1024);
    gemm_mlp2_k<<<512, 256, 0, stream>>>(mid, wt2, b2, (float*)d_out, x2, 4096);
}

// Round 18
// 240.025 us; speedup vs baseline: 1.0020x; 1.0020x over previous
//
#include <hip/hip_runtime.h>
#include <hip/hip_bf16.h>

typedef unsigned short u16;
typedef unsigned int u32;
typedef __attribute__((ext_vector_type(8))) unsigned short us8;
typedef __attribute__((ext_vector_type(4))) unsigned short us4;
typedef __attribute__((ext_vector_type(2))) unsigned int u32x2;
typedef __attribute__((ext_vector_type(8))) short bf16x8;   // 8 bf16 in 4 VGPRs
typedef __attribute__((ext_vector_type(4))) float f32x4;

#define QSCALE 0.18033688011112042f   // 0.125 * log2(e): folded into Q epilogue

__device__ __forceinline__ u16 f2bf(float f) {
    __hip_bfloat16 h = __float2bfloat16(f);   // RNE
    return __builtin_bit_cast(u16, h);
}
// pack two floats to bf16 pair in one instr (lo in [15:0], hi in [31:16])
__device__ __forceinline__ u32 cvtpk(float lo, float hi) {
    u32 r;
    asm("v_cvt_pk_bf16_f32 %0, %1, %2" : "=v"(r) : "v"(lo), "v"(hi));
    return r;
}
// raw v_exp_f32 (no libm range-guard code); fine for |x| < 126
__device__ __forceinline__ float ex2(float x) {
    return __builtin_amdgcn_exp2f(x);
}
// tanh-form GELU, 7 VALU ops, inf-safe at both tails (max err ~3e-4)
__device__ __forceinline__ float gelu7(float v) {
    const float a = v * fmaf(0.10294324f, v * v, 2.3022082f);
    const float E = ex2(a);
    return v - v * __builtin_amdgcn_rcpf(1.0f + E);
}
// async global(16B/lane) -> LDS (wave-uniform base + lane*16)
__device__ __forceinline__ void gll16(const u16* g, u16* l) {
    __builtin_amdgcn_global_load_lds(
        (const __attribute__((address_space(1))) unsigned int*)g,
        (__attribute__((address_space(3))) unsigned int*)l, 16, 0, 0);
}
template<int N> __device__ __forceinline__ void waitv() {
    if constexpr (N == 0)       asm volatile("s_waitcnt vmcnt(0)" ::: "memory");
    else if constexpr (N == 4)  asm volatile("s_waitcnt vmcnt(4)" ::: "memory");
    else if constexpr (N == 6)  asm volatile("s_waitcnt vmcnt(6)" ::: "memory");
    else if constexpr (N == 8)  asm volatile("s_waitcnt vmcnt(8)" ::: "memory");
    else static_assert(N == 0, "unsupported vmcnt");
}

// ---------------------------------------------------------------------------
// fp32 [KK][NN] -> bf16 transposed [NN][KK]
// ---------------------------------------------------------------------------
__global__ void tcvt_k(const float* __restrict__ W, u16* __restrict__ Wt, int KK, int NN)
{
    __shared__ float tile[32][33];
    const int n0 = blockIdx.x * 32, k0 = blockIdx.y * 32;
    const int tx = threadIdx.x, ty = threadIdx.y;
    #pragma unroll
    for (int j = ty; j < 32; j += 8)
        tile[j][tx] = W[(size_t)(k0 + j) * NN + n0 + tx];
    __syncthreads();
    #pragma unroll
    for (int j = ty; j < 32; j += 8)
        Wt[(size_t)(n0 + j) * KK + k0 + tx] = f2bf(tile[tx][j]);
}

// four 1024x1024 transposes in one launch (z selects weight; outputs contiguous)
__global__ void tcvt4_k(const float* __restrict__ a, const float* __restrict__ b,
                        const float* __restrict__ c, const float* __restrict__ d,
                        u16* __restrict__ out)
{
    __shared__ float tile[32][33];
    const int z = blockIdx.z;
    const float* W = (z == 0) ? a : (z == 1) ? b : (z == 2) ? c : d;
    u16* Wt = out + (size_t)z * 1024 * 1024;
    const int n0 = blockIdx.x * 32, k0 = blockIdx.y * 32;
    const int tx = threadIdx.x, ty = threadIdx.y;
    #pragma unroll
    for (int j = ty; j < 32; j += 8)
        tile[j][tx] = W[(size_t)(k0 + j) * 1024 + n0 + tx];
    __syncthreads();
    #pragma unroll
    for (int j = ty; j < 32; j += 8)
        Wt[(size_t)(n0 + j) * 1024 + k0 + tx] = f2bf(tile[tx][j]);
}

// ---------------------------------------------------------------------------
// bf16 [32][2048][64] -> [32][64][2048]  (V transpose for PV B-operand reads)
// ---------------------------------------------------------------------------
__global__ __launch_bounds__(256) void vtr_k(const u16* __restrict__ Vb, u16* __restrict__ Vt)
{
    __shared__ u16 t[64][72];
    const int bh = blockIdx.y, s0 = blockIdx.x * 64;
    const int tid = threadIdx.x;
    const size_t ibase = (size_t)bh * 2048 * 64 + (size_t)s0 * 64;
    #pragma unroll
    for (int c = tid; c < 512; c += 256) {
        const us8 v = *(const us8*)(Vb + ibase + (size_t)(c >> 3) * 64 + (c & 7) * 8);
        *(us8*)(&t[c >> 3][(c & 7) * 8]) = v;
    }
    __syncthreads();
    const size_t obase = (size_t)bh * 64 * 2048 + s0;
    #pragma unroll
    for (int c = tid; c < 512; c += 256) {
        const int hd = c >> 3, sl0 = (c & 7) * 8;
        us8 v;
        #pragma unroll
        for (int j = 0; j < 8; j++) v[j] = t[sl0 + j][hd];
        *(us8*)(Vt + obase + (size_t)hd * 2048 + sl0) = v;
    }
}

// ---------------------------------------------------------------------------
// LayerNorm (D=1024): wave-per-row, 4 rows per block (grid 1024).
// Wave-local shfl_xor reduction only -- no LDS, no barrier.
// ---------------------------------------------------------------------------
__global__ __launch_bounds__(256) void ln_k(const float* __restrict__ x,
                                            const float* __restrict__ g,
                                            const float* __restrict__ b,
                                            u16* __restrict__ h)
{
    const int l = threadIdx.x & 63, w = threadIdx.x >> 6;
    const int row = blockIdx.x * 4 + w;
    const float* xr = x + (size_t)row * 1024;
    float4 v[4];
    float sum = 0.0f, sq = 0.0f;
    #pragma unroll
    for (int i = 0; i < 4; i++) {
        v[i] = *(const float4*)(xr + i * 256 + l * 4);
        sum += (v[i].x + v[i].y) + (v[i].z + v[i].w);
        sq  += (v[i].x * v[i].x + v[i].y * v[i].y)
             + (v[i].z * v[i].z + v[i].w * v[i].w);
    }
    #pragma unroll
    for (int off = 32; off >= 1; off >>= 1) {
        sum += __shfl_xor(sum, off);
        sq  += __shfl_xor(sq, off);
    }
    const float mean = sum * (1.0f / 1024.0f);
    const float var  = sq * (1.0f / 1024.0f) - mean * mean;
    const float inv  = rsqrtf(var + 1e-6f);
    u16* hr = h + (size_t)row * 1024;
    #pragma unroll
    for (int i = 0; i < 4; i++) {
        const int c = i * 256 + l * 4;
        us4 o;
        o[0] = f2bf((v[i].x - mean) * inv * g[c + 0] + b[c + 0]);
        o[1] = f2bf((v[i].y - mean) * inv * g[c + 1] + b[c + 1]);
        o[2] = f2bf((v[i].z - mean) * inv * g[c + 2] + b[c + 2]);
        o[3] = f2bf((v[i].w - mean) * inv * g[c + 3] + b[c + 3]);
        *(us4*)(hr + c) = o;
    }
}

// ---------------------------------------------------------------------------
// Pipelined MFMA GEMM body: C[M,N] = A[M,K] @ Bt[N,K]^T, row stride Kld
// (Kld == K except split-K callers). TM x 128 tile, BK in {32,64},
// double-buffered LDS, gll16 staging. Per K-step: barrier; stage(next);
// vmcnt(NI); barrier; ds_read+MFMA. LDS dest LINEAR; global SOURCE col-block
// inverse-swizzled; reads swizzled (rule #21).
// EPI: 0 = bias, *scale, bf16 scatter to [B*H][S][HD]
//      1/3 = bias + addsrc(f32) residual -> f32 out (stride 1024)
//      2 = bias + tanh-form GELU (gelu7) -> bf16 out (stride 4096)
//      4 = raw f32 partial (no bias) -> f32 out (stride 1024)  [split-K]
// ---------------------------------------------------------------------------
template<int EPI, int TM, int BK>
__device__ __forceinline__ void gemm_body(const u16* __restrict__ A,
                                          const u16* __restrict__ Bt,
                                          const float* __restrict__ bias,
                                          void* __restrict__ outp,
                                          const float* __restrict__ addsrc,
                                          int K, int Kld, float scale,
                                          int m0, int n0)
{
    constexpr int MI  = TM / 32;
    constexpr int ASZ = TM * BK;
    constexpr int BSZ = 128 * BK;
    constexpr int RPI = 512 / BK;
    constexpr int NIA = (TM / 4) / RPI;
    constexpr int NIB = 32 / RPI;
    constexpr int NI  = NIA + NIB;
    __shared__ u16 As[2 * ASZ];
    __shared__ u16 Bs[2 * BSZ];
    const int tid = threadIdx.x;
    const int l = tid & 63, w = tid >> 6;
    const int wr = w >> 1, wc = w & 1;
    const int lr = l & 15, lg = l >> 4;

    int srow, sblk;
    if constexpr (BK == 32) { srow = l >> 2; sblk = (l & 3) ^ ((l >> 3) & 3); }
    else                    { srow = l >> 3; sblk = (l & 7) ^ (l >> 3); }
    const u16* gA = A  + (size_t)(m0 + w * (TM / 4) + srow) * Kld + sblk * 8;
    const u16* gB = Bt + (size_t)(n0 + w * 32 + srow) * Kld + sblk * 8;
    const size_t rowKi = (size_t)RPI * Kld;
    u16* const lA0 = As + w * (TM / 4) * BK;
    u16* const lB0 = Bs + w * 32 * BK;

    f32x4 acc[MI][4];
    #pragma unroll
    for (int i = 0; i < MI; i++)
        #pragma unroll
        for (int j = 0; j < 4; j++) acc[i][j] = (f32x4)(0.0f);

    auto stage = [&](int buf, int kb) {
        u16* la = lA0 + buf * ASZ;
        u16* lb = lB0 + buf * BSZ;
        #pragma unroll
        for (int i = 0; i < NIA; i++) gll16(gA + kb + i * rowKi, la + i * 512);
        #pragma unroll
        for (int i = 0; i < NIB; i++) gll16(gB + kb + i * rowKi, lb + i * 512);
    };

    const int nK = K / BK;
    stage(0, 0);
    int cur = 0;
    for (int kt = 0; kt < nK; ++kt) {
        __builtin_amdgcn_sched_barrier(0);
        __builtin_amdgcn_s_barrier();
        __builtin_amdgcn_sched_barrier(0);
        if (kt + 1 < nK) {
            stage(cur ^ 1, (kt + 1) * BK);
            waitv<NI>();
        } else {
            waitv<0>();
        }
        __builtin_amdgcn_s_barrier();
        __builtin_amdgcn_sched_barrier(0);

        const u16* as = As + cur * ASZ;
        const u16* bs = Bs + cur * BSZ;
        #pragma unroll
        for (int ks = 0; ks < BK / 32; ks++) {
            int off;
            if constexpr (BK == 32) off = (lg ^ ((lr >> 1) & 3)) * 8;
            else                    off = ((ks * 4 + lg) ^ (lr & 7)) * 8;
            bf16x8 af[MI], bf[4];
            #pragma unroll
            for (int mi = 0; mi < MI; mi++)
                af[mi] = *(const bf16x8*)(as + (wr * (MI * 16) + mi * 16 + lr) * BK + off);
            #pragma unroll
            for (int ni = 0; ni < 4; ni++)
                bf[ni] = *(const bf16x8*)(bs + (wc * 64 + ni * 16 + lr) * BK + off);
            #pragma unroll
            for (int mi = 0; mi < MI; mi++)
                #pragma unroll
                for (int ni = 0; ni < 4; ni++)
                    acc[mi][ni] = __builtin_amdgcn_mfma_f32_16x16x32_bf16(
                        af[mi], bf[ni], acc[mi][ni], 0, 0, 0);
        }
        cur ^= 1;
    }

    const int r0 = lg * 4;
    #pragma unroll
    for (int mi = 0; mi < MI; mi++) {
        #pragma unroll
        for (int ni = 0; ni < 4; ni++) {
            const int col = n0 + wc * 64 + ni * 16 + lr;
            float bv;
            if constexpr (EPI == 4) bv = 0.0f; else bv = bias[col];
            #pragma unroll
            for (int r = 0; r < 4; r++) {
                const int row = m0 + wr * (MI * 16) + mi * 16 + r0 + r;
                const float v = acc[mi][ni][r] + bv;
                if constexpr (EPI == 0) {
                    const int bb = row >> 11, s = row & 2047;
                    const int hh = col >> 6, hd = col & 63;
                    ((u16*)outp)[(((size_t)(bb * 16 + hh) * 2048) + s) * 64 + hd] = f2bf(v * scale);
                } else if constexpr (EPI == 1 || EPI == 3) {
                    const size_t idx = (size_t)row * 1024 + col;
                    ((float*)outp)[idx] = addsrc[idx] + v;
                } else if constexpr (EPI == 2) {
                    ((u16*)outp)[(size_t)row * 4096 + col] = f2bf(gelu7(v));
                } else {
                    ((float*)outp)[(size_t)row * 1024 + col] = v;
                }
            }
        }
    }
}

// 1-D grid, bijective XCD swizzle (nwg % 8 == 0), n-fast within an XCD.
template<int EPI, int TM, int BK, int NX>
__global__ __launch_bounds__(256) void gemm_k(const u16* __restrict__ A,
                                              const u16* __restrict__ Bt,
                                              const float* __restrict__ bias,
                                              void* __restrict__ outp,
                                              const float* __restrict__ addsrc,
                                              int K)
{
    const int nwg = gridDim.x;
    const int s = (blockIdx.x & 7) * (nwg >> 3) + (blockIdx.x >> 3);
    gemm_body<EPI, TM, BK>(A, Bt, bias, outp, addsrc, K, K, 1.0f,
                           (s / NX) * TM, (s % NX) * 128);
}

// MLP2 split-K x2 at the MFMA-bound ratio (TM=128/BK=32, 32KB LDS):
// grid 512 = 2kz x 32m x 8n, 2 blocks/CU. kz in {0,1} selects the K-half;
// f32 partials to P[kz][4096][1024]. XCDs 0-3 own kz=0, 4-7 kz=1; within
// an XCD n-fast over 8m x 8n.
__global__ __launch_bounds__(256) void gemm_mlp2_k(const u16* __restrict__ A,
                                                   const u16* __restrict__ Bt,
                                                   float* __restrict__ P)
{
    const int s = (blockIdx.x & 7) * 64 + (blockIdx.x >> 3);   // nwg = 512
    const int kz = s >> 8, r = s & 255;
    gemm_body<4, 128, 32>(A + kz * 2048, Bt + kz * 2048, nullptr,
                          P + (size_t)kz * 4096 * 1024, nullptr,
                          2048, 4096, 1.0f, (r >> 3) * 128, (r & 7) * 128);
}

// reduce: d_out = x2 + b2 + P0 + P1 (float4, 4096 blocks x 256 thr)
__global__ __launch_bounds__(256) void mlp2_red_k(const float* __restrict__ P0,
                                                  const float* __restrict__ P1,
                                                  const float* __restrict__ x2,
                                                  const float* __restrict__ b2,
                                                  float* __restrict__ out)
{
    const size_t i = ((size_t)blockIdx.x * 256 + threadIdx.x) * 4;
    const float4 a = *(const float4*)(P0 + i);
    const float4 b = *(const float4*)(P1 + i);
    const float4 c = *(const float4*)(x2 + i);
    const int col = (int)(i & 1023);
    const float4 bb = *(const float4*)(b2 + col);
    float4 r;
    r.x = c.x + bb.x + a.x + b.x;
    r.y = c.y + bb.y + a.y + b.y;
    r.z = c.z + bb.z + a.z + b.z;
    r.w = c.w + bb.w + a.w + b.w;
    *(float4*)(out + i) = r;
}

// MLP1 (TM=64/BK=64, grid 2048): XCD owns 16m x 16n super-tile, walked in
// 4 generations of 16m x 4n (m-fast inner); generation working set ~3MB.
__global__ __launch_bounds__(256) void gemm_mlp1_k(const u16* __restrict__ A,
                                                   const u16* __restrict__ Bt,
                                                   const float* __restrict__ bias,
                                                   void* __restrict__ outp,
                                                   int K)
{
    const int x = blockIdx.x & 7;
    const int idx = blockIdx.x >> 3;          // 0..255
    const int m = (x >> 1) * 16 + (idx & 15);
    const int n = (x & 1) * 16 + (idx >> 6) * 4 + ((idx >> 4) & 3);
    gemm_body<2, 64, 64>(A, Bt, bias, outp, nullptr, K, K, 1.0f, m * 64, n * 128);
}

// fused QKV (grid 768): XCD owns a disjoint 4-m-panel slice of shared A.
__global__ __launch_bounds__(256) void gemm_qkv_k(const u16* __restrict__ A,
                                                  const u16* __restrict__ WtBase,
                                                  const float* __restrict__ bq,
                                                  const float* __restrict__ bk,
                                                  const float* __restrict__ bv,
                                                  u16* __restrict__ outBase)
{
    const int x = blockIdx.x & 7;
    const int i = blockIdx.x >> 3;            // 0..95
    const int m = x * 4 + (i & 3);            // 0..31
    const int rest = i >> 2;                  // 0..23
    const int z = rest >> 3, n = rest & 7;
    const u16* Bt = WtBase + (size_t)z * 1024 * 1024;
    const float* bias = (z == 0) ? bq : (z == 1) ? bk : bv;
    u16* outp = outBase + (size_t)z * 4096 * 1024;
    const float scale = (z == 0) ? QSCALE : 1.0f;
    gemm_body<0, 128, 32>(A, Bt, bias, outp, nullptr, 1024, 1024, scale,
                          m * 128, n * 128);
}

// ---------------------------------------------------------------------------
// MFMA flash attention, swapped-QK^T, no max tracking; KV-TILE = 128 (R16):
// one barrier pair + one counted vmcnt per 128 kv (two 64-kv compute passes
// inside). Wave owns 32 q rows as two 16-row groups sharing every K/V
// fragment read. Grid 512 (2 blocks/CU, LDS 80KB).
// ---------------------------------------------------------------------------
__global__ __launch_bounds__(256) void attn_mfma_k(
    const u16* __restrict__ Qb, const u16* __restrict__ Kb,
    const u16* __restrict__ Vt, u16* __restrict__ Oo)
{
    __shared__ u16 Kl[2][128 * 64];    // [kv][hd]
    __shared__ u16 Vl[2][64 * 128];    // [hd][kv]
    __shared__ u16 Pl[4][32 * 64];     // per-wave P: 32 q rows

    const int tid = threadIdx.x;
    const int l = tid & 63, w = tid >> 6;
    const int lr = l & 15, lg = l >> 4;
    const int bid = blockIdx.x;
    const int bh = (bid & 7) * 4 + ((bid >> 3) >> 4);   // 4 heads per XCD
    const int qblk = (bid >> 3) & 15;
    const size_t base = (size_t)bh * 2048 * 64;
    const size_t vbase = (size_t)bh * 64 * 2048;
    const int q0 = qblk * 128 + w * 32;

    bf16x8 qf[2][2];
    #pragma unroll
    for (int g = 0; g < 2; g++)
        #pragma unroll
        for (int ks = 0; ks < 2; ks++)
            qf[g][ks] = *(const bf16x8*)(Qb + base + (size_t)(q0 + g * 16 + lr) * 64
                                         + ks * 32 + lg * 8);

    bf16x8 onef;
    #pragma unroll
    for (int j = 0; j < 8; j++) onef[j] = (short)0x3F80;

    f32x4 o_[2][4];
    f32x4 ol[2];
    #pragma unroll
    for (int g = 0; g < 2; g++) {
        #pragma unroll
        for (int r = 0; r < 4; r++) ol[g][r] = 0.0f;
        #pragma unroll
        for (int ni = 0; ni < 4; ni++) o_[g][ni] = (f32x4)(0.0f);
    }

    u16* const plw = &Pl[w][0];
    u16* pw_[2][4];
    const u16* pr_[2][2];
    #pragma unroll
    for (int g = 0; g < 2; g++) {
        #pragma unroll
        for (int ni = 0; ni < 4; ni++)
            pw_[g][ni] = plw + (g * 16 + lr) * 64
                       + (((ni * 2 + (lg >> 1)) ^ (lr & 7)) * 8 + (lg & 1) * 4);
        pr_[g][0] = plw + (g * 16 + lr) * 64 + ((lg ^ (lr & 7)) * 8);
        pr_[g][1] = plw + (g * 16 + lr) * 64 + (((4 + lg) ^ (lr & 7)) * 8);
    }

    const u16* gK = Kb + base + (size_t)(w * 32 + (l >> 3)) * 64
                  + (((l & 7) ^ (l >> 3)) * 8);
    u16* const kd = &Kl[0][0] + w * 32 * 64;

    const u16* gVsrc[4];
    #pragma unroll
    for (int i = 0; i < 4; i++) {
        const int vrow = w * 16 + i * 4 + (l >> 4);
        gVsrc[i] = Vt + vbase + (size_t)vrow * 2048
                 + (((l & 15) ^ (i * 4 + (l >> 4))) * 8);
    }
    u16* const vd = &Vl[0][0] + w * 16 * 128;

    auto stageT = [&](int buf, int kv) {
        u16* kdb = kd + buf * 8192;
        u16* vdb = vd + buf * 8192;
        #pragma unroll
        for (int i = 0; i < 4; i++)
            gll16(gK + (size_t)kv * 64 + i * 512, kdb + i * 512);
        #pragma unroll
        for (int i = 0; i < 4; i++)
            gll16(gVsrc[i] + kv, vdb + i * 512);
    };

    stageT(0, 0);
    int cur = 0;
    for (int t = 0; t < 16; ++t) {
        __builtin_amdgcn_sched_barrier(0);
        __builtin_amdgcn_s_barrier();
        __builtin_amdgcn_sched_barrier(0);
        if (t < 15) {
            stageT(cur ^ 1, (t + 1) * 128);
            waitv<8>();
        } else {
            waitv<0>();
        }
        __builtin_amdgcn_s_barrier();
        __builtin_amdgcn_sched_barrier(0);

        #pragma unroll
        for (int s = 0; s < 2; s++) {
            f32x4 s_[2][4];
            #pragma unroll
            for (int g = 0; g < 2; g++)
                #pragma unroll
                for (int ni = 0; ni < 4; ni++) s_[g][ni] = (f32x4)(0.0f);
            __builtin_amdgcn_s_setprio(1);
            #pragma unroll
            for (int ks = 0; ks < 2; ks++)
                #pragma unroll
                for (int ni = 0; ni < 4; ni++) {
                    const int row = ni * 16 + lr;
                    const bf16x8 kf = *(const bf16x8*)(
                        &Kl[cur][(s * 64 + row) * 64 + (((ks * 4 + lg) ^ (row & 7)) * 8)]);
                    s_[0][ni] = __builtin_amdgcn_mfma_f32_16x16x32_bf16(kf, qf[0][ks], s_[0][ni], 0, 0, 0);
                    s_[1][ni] = __builtin_amdgcn_mfma_f32_16x16x32_bf16(kf, qf[1][ks], s_[1][ni], 0, 0, 0);
                }
            __builtin_amdgcn_s_setprio(0);

            #pragma unroll
            for (int g = 0; g < 2; g++)
                #pragma unroll
                for (int ni = 0; ni < 4; ni++) {
                    u32x2 pv;
                    pv[0] = cvtpk(ex2(s_[g][ni][0]), ex2(s_[g][ni][1]));
                    pv[1] = cvtpk(ex2(s_[g][ni][2]), ex2(s_[g][ni][3]));
                    *(u32x2*)pw_[g][ni] = pv;
                }

            __builtin_amdgcn_s_setprio(1);
            #pragma unroll
            for (int ks = 0; ks < 2; ks++) {
                const bf16x8 pf0 = *(const bf16x8*)pr_[0][ks];
                const bf16x8 pf1 = *(const bf16x8*)pr_[1][ks];
                ol[0] = __builtin_amdgcn_mfma_f32_16x16x32_bf16(pf0, onef, ol[0], 0, 0, 0);
                ol[1] = __builtin_amdgcn_mfma_f32_16x16x32_bf16(pf1, onef, ol[1], 0, 0, 0);
                #pragma unroll
                for (int ni = 0; ni < 4; ni++) {
                    const int row = ni * 16 + lr;
                    const int chunk = s * 8 + ks * 4 + lg;
                    const bf16x8 vf = *(const bf16x8*)(
                        &Vl[cur][row * 128 + ((chunk ^ (row & 15)) * 8)]);
                    o_[0][ni] = __builtin_amdgcn_mfma_f32_16x16x32_bf16(pf0, vf, o_[0][ni], 0, 0, 0);
                    o_[1][ni] = __builtin_amdgcn_mfma_f32_16x16x32_bf16(pf1, vf, o_[1][ni], 0, 0, 0);
                }
            }
            __builtin_amdgcn_s_setprio(0);
        }
        cur ^= 1;
    }

    const int bb = bh >> 4, hh = bh & 15;
    #pragma unroll
    for (int g = 0; g < 2; g++)
        #pragma unroll
        for (int r = 0; r < 4; r++) {
            const float inv = 1.0f / ol[g][r];
            const int qrow = q0 + g * 16 + lg * 4 + r;
            u16* dst = Oo + ((size_t)(bb * 2048 + qrow)) * 1024 + hh * 64;
            #pragma unroll
            for (int ni = 0; ni < 4; ni++)
                dst[ni * 16 + lr] = f2bf(o_[g][ni][r] * inv);
        }
}

// ---------------------------------------------------------------------------
extern "C" void kernel_launch(void* const* d_in, const int* in_sizes, int n_in,
                              void* d_out, int out_size, void* d_ws, size_t ws_size,
                              hipStream_t stream)
{
    const float* x     = (const float*)d_in[0];
    const float* ln1_g = (const float*)d_in[1];
    const float* ln1_b = (const float*)d_in[2];
    const float* wq    = (const float*)d_in[3];
    const float* bq    = (const float*)d_in[4];
    const float* wk    = (const float*)d_in[5];
    const float* bk    = (const float*)d_in[6];
    const float* wv    = (const float*)d_in[7];
    const float* bv    = (const float*)d_in[8];
    const float* wo    = (const float*)d_in[9];
    const float* bo    = (const float*)d_in[10];
    const float* ln2_g = (const float*)d_in[11];
    const float* ln2_b = (const float*)d_in[12];
    const float* w1    = (const float*)d_in[13];
    const float* b1    = (const float*)d_in[14];
    const float* w2    = (const float*)d_in[15];
    const float* b2    = (const float*)d_in[16];

    char* ws = (char*)d_ws;
    size_t off = 0;
    auto alloc = [&](size_t bytes) {
        char* p = ws + off;
        off += (bytes + 255) & ~(size_t)255;
        return p;
    };
    // NOTE: wtq/wtk/wtv/wto must stay contiguous (tcvt4_k / gemm_qkv_k index
    // by z), as must qb/kb/vb (qb/vb double as split-K partials after
    // attention+O-proj consume them). Each alloc is a multiple of 256B.
    u16* wtq = (u16*)alloc((size_t)1024 * 1024 * 2);
    u16* wtk = (u16*)alloc((size_t)1024 * 1024 * 2);
    u16* wtv = (u16*)alloc((size_t)1024 * 1024 * 2);
    u16* wto = (u16*)alloc((size_t)1024 * 1024 * 2);
    u16* wt1 = (u16*)alloc((size_t)4096 * 1024 * 2);  // [MLP][D]
    u16* wt2 = (u16*)alloc((size_t)1024 * 4096 * 2);  // [D][MLP]
    u16* h1  = (u16*)alloc((size_t)4096 * 1024 * 2);
    u16* qb  = (u16*)alloc((size_t)4096 * 1024 * 2);  // [B*H][S][HD]
    u16* kb  = (u16*)alloc((size_t)4096 * 1024 * 2);
    u16* vb  = (u16*)alloc((size_t)4096 * 1024 * 2);
    u16* ao  = (u16*)alloc((size_t)4096 * 1024 * 2);  // [B,S,D]
    float* x2 = (float*)alloc((size_t)4096 * 1024 * 4);
    u16* h2  = (u16*)alloc((size_t)4096 * 1024 * 2);
    u16* mid = (u16*)alloc((size_t)4096 * 4096 * 2);
    // V^T [32][64][2048] aliases `mid` (mid is first written AFTER attention).
    u16* vt  = mid;
    // split-K partials alias qb..vb (dead after O-proj): 2 x 16.78MB f32
    float* p0 = (float*)qb;
    float* p1 = (float*)vb;
    (void)ws_size;
    (void)wtk; (void)wtv;

    const dim3 tb(32, 8);
    tcvt4_k<<<dim3(32, 32, 4), tb, 0, stream>>>(wq, wk, wv, wo, wtq);
    tcvt_k<<<dim3(128, 32), tb, 0, stream>>>(w1, wt1, 1024, 4096);
    tcvt_k<<<dim3(32, 128), tb, 0, stream>>>(w2, wt2, 4096, 1024);

    ln_k<<<1024, 256, 0, stream>>>(x, ln1_g, ln1_b, h1);

    gemm_qkv_k<<<768, 256, 0, stream>>>(h1, wtq, bq, bk, bv, qb);

    vtr_k<<<dim3(32, 32), 256, 0, stream>>>(vb, vt);
    attn_mfma_k<<<512, 256, 0, stream>>>(qb, kb, vt, ao);

    gemm_k<1, 64, 64, 8><<<512, 256, 0, stream>>>(ao, wto, bo, x2, x, 1024);

    ln_k<<<1024, 256, 0, stream>>>(x2, ln2_g, ln2_b, h2);

    gemm_mlp1_k<<<2048, 256, 0, stream>>>(h2, wt1, b1, mid, 1024);

    gemm_mlp2_k<<<512, 256, 0, stream>>>(mid, wt2, p0);
    mlp2_red_k<<<4096, 256, 0, stream>>>(p0, p1, x2, b2, (float*)d_out);
}

// Round 19
// 236.167 us; speedup vs baseline: 1.0184x; 1.0163x over previous
//
#include <hip/hip_runtime.h>
#include <hip/hip_bf16.h>

typedef unsigned short u16;
typedef unsigned int u32;
typedef __attribute__((ext_vector_type(8))) unsigned short us8;
typedef __attribute__((ext_vector_type(4))) unsigned short us4;
typedef __attribute__((ext_vector_type(2))) unsigned int u32x2;
typedef __attribute__((ext_vector_type(8))) short bf16x8;   // 8 bf16 in 4 VGPRs
typedef __attribute__((ext_vector_type(4))) float f32x4;

#define QSCALE 0.18033688011112042f   // 0.125 * log2(e): folded into Q epilogue

__device__ __forceinline__ u16 f2bf(float f) {
    __hip_bfloat16 h = __float2bfloat16(f);   // RNE
    return __builtin_bit_cast(u16, h);
}
// pack two floats to bf16 pair in one instr (lo in [15:0], hi in [31:16])
__device__ __forceinline__ u32 cvtpk(float lo, float hi) {
    u32 r;
    asm("v_cvt_pk_bf16_f32 %0, %1, %2" : "=v"(r) : "v"(lo), "v"(hi));
    return r;
}
// raw v_exp_f32 (no libm range-guard code); fine for |x| < 126
__device__ __forceinline__ float ex2(float x) {
    return __builtin_amdgcn_exp2f(x);
}
// tanh-form GELU, 7 VALU ops, inf-safe at both tails (max err ~3e-4)
__device__ __forceinline__ float gelu7(float v) {
    const float a = v * fmaf(0.10294324f, v * v, 2.3022082f);
    const float E = ex2(a);
    return v - v * __builtin_amdgcn_rcpf(1.0f + E);
}
// async global(16B/lane) -> LDS (wave-uniform base + lane*16)
__device__ __forceinline__ void gll16(const u16* g, u16* l) {
    __builtin_amdgcn_global_load_lds(
        (const __attribute__((address_space(1))) unsigned int*)g,
        (__attribute__((address_space(3))) unsigned int*)l, 16, 0, 0);
}
template<int N> __device__ __forceinline__ void waitv() {
    if constexpr (N == 0)       asm volatile("s_waitcnt vmcnt(0)" ::: "memory");
    else if constexpr (N == 4)  asm volatile("s_waitcnt vmcnt(4)" ::: "memory");
    else if constexpr (N == 6)  asm volatile("s_waitcnt vmcnt(6)" ::: "memory");
    else if constexpr (N == 8)  asm volatile("s_waitcnt vmcnt(8)" ::: "memory");
    else static_assert(N == 0, "unsupported vmcnt");
}

// ---------------------------------------------------------------------------
// fp32 [KK][NN] -> bf16 transposed [NN][KK]
// ---------------------------------------------------------------------------
__global__ void tcvt_k(const float* __restrict__ W, u16* __restrict__ Wt, int KK, int NN)
{
    __shared__ float tile[32][33];
    const int n0 = blockIdx.x * 32, k0 = blockIdx.y * 32;
    const int tx = threadIdx.x, ty = threadIdx.y;
    #pragma unroll
    for (int j = ty; j < 32; j += 8)
        tile[j][tx] = W[(size_t)(k0 + j) * NN + n0 + tx];
    __syncthreads();
    #pragma unroll
    for (int j = ty; j < 32; j += 8)
        Wt[(size_t)(n0 + j) * KK + k0 + tx] = f2bf(tile[tx][j]);
}

// four 1024x1024 transposes in one launch (z selects weight; outputs contiguous)
__global__ void tcvt4_k(const float* __restrict__ a, const float* __restrict__ b,
                        const float* __restrict__ c, const float* __restrict__ d,
                        u16* __restrict__ out)
{
    __shared__ float tile[32][33];
    const int z = blockIdx.z;
    const float* W = (z == 0) ? a : (z == 1) ? b : (z == 2) ? c : d;
    u16* Wt = out + (size_t)z * 1024 * 1024;
    const int n0 = blockIdx.x * 32, k0 = blockIdx.y * 32;
    const int tx = threadIdx.x, ty = threadIdx.y;
    #pragma unroll
    for (int j = ty; j < 32; j += 8)
        tile[j][tx] = W[(size_t)(k0 + j) * 1024 + n0 + tx];
    __syncthreads();
    #pragma unroll
    for (int j = ty; j < 32; j += 8)
        Wt[(size_t)(n0 + j) * 1024 + k0 + tx] = f2bf(tile[tx][j]);
}

// ---------------------------------------------------------------------------
// bf16 [32][2048][64] -> [32][64][2048]  (V transpose for PV B-operand reads)
// ---------------------------------------------------------------------------
__global__ __launch_bounds__(256) void vtr_k(const u16* __restrict__ Vb, u16* __restrict__ Vt)
{
    __shared__ u16 t[64][72];
    const int bh = blockIdx.y, s0 = blockIdx.x * 64;
    const int tid = threadIdx.x;
    const size_t ibase = (size_t)bh * 2048 * 64 + (size_t)s0 * 64;
    #pragma unroll
    for (int c = tid; c < 512; c += 256) {
        const us8 v = *(const us8*)(Vb + ibase + (size_t)(c >> 3) * 64 + (c & 7) * 8);
        *(us8*)(&t[c >> 3][(c & 7) * 8]) = v;
    }
    __syncthreads();
    const size_t obase = (size_t)bh * 64 * 2048 + s0;
    #pragma unroll
    for (int c = tid; c < 512; c += 256) {
        const int hd = c >> 3, sl0 = (c & 7) * 8;
        us8 v;
        #pragma unroll
        for (int j = 0; j < 8; j++) v[j] = t[sl0 + j][hd];
        *(us8*)(Vt + obase + (size_t)hd * 2048 + sl0) = v;
    }
}

// ---------------------------------------------------------------------------
// LayerNorm (D=1024): wave-per-row, 4 rows per block (grid 1024).
// Wave-local shfl_xor reduction only -- no LDS, no barrier.
// ---------------------------------------------------------------------------
__global__ __launch_bounds__(256) void ln_k(const float* __restrict__ x,
                                            const float* __restrict__ g,
                                            const float* __restrict__ b,
                                            u16* __restrict__ h)
{
    const int l = threadIdx.x & 63, w = threadIdx.x >> 6;
    const int row = blockIdx.x * 4 + w;
    const float* xr = x + (size_t)row * 1024;
    float4 v[4];
    float sum = 0.0f, sq = 0.0f;
    #pragma unroll
    for (int i = 0; i < 4; i++) {
        v[i] = *(const float4*)(xr + i * 256 + l * 4);
        sum += (v[i].x + v[i].y) + (v[i].z + v[i].w);
        sq  += (v[i].x * v[i].x + v[i].y * v[i].y)
             + (v[i].z * v[i].z + v[i].w * v[i].w);
    }
    #pragma unroll
    for (int off = 32; off >= 1; off >>= 1) {
        sum += __shfl_xor(sum, off);
        sq  += __shfl_xor(sq, off);
    }
    const float mean = sum * (1.0f / 1024.0f);
    const float var  = sq * (1.0f / 1024.0f) - mean * mean;
    const float inv  = rsqrtf(var + 1e-6f);
    u16* hr = h + (size_t)row * 1024;
    #pragma unroll
    for (int i = 0; i < 4; i++) {
        const int c = i * 256 + l * 4;
        us4 o;
        o[0] = f2bf((v[i].x - mean) * inv * g[c + 0] + b[c + 0]);
        o[1] = f2bf((v[i].y - mean) * inv * g[c + 1] + b[c + 1]);
        o[2] = f2bf((v[i].z - mean) * inv * g[c + 2] + b[c + 2]);
        o[3] = f2bf((v[i].w - mean) * inv * g[c + 3] + b[c + 3]);
        *(us4*)(hr + c) = o;
    }
}

// ---------------------------------------------------------------------------
// Pipelined MFMA GEMM body: C[M,N] = A[M,K] @ Bt[N,K]^T (R16 form).
// TM x 128 tile, BK in {32,64}, double-buffered LDS, gll16 staging.
// Per K-step: barrier; stage(next); vmcnt(NI); barrier; ds_read+MFMA.
// LDS dest LINEAR; global SOURCE col-block inverse-swizzled; reads swizzled
// (rule #21). BK=32: 4-blk swizzle ^((lr>>1)&3); BK=64: 8-blk ^(lr&7).
// EPI: 0 = bias, *scale, bf16 scatter to [B*H][S][HD]
//      1/3 = bias + addsrc(f32) residual -> f32 out (stride 1024)
//      2 = bias + tanh-form GELU (gelu7) -> bf16 out (stride 4096)
// ---------------------------------------------------------------------------
template<int EPI, int TM, int BK>
__device__ __forceinline__ void gemm_body(const u16* __restrict__ A,
                                          const u16* __restrict__ Bt,
                                          const float* __restrict__ bias,
                                          void* __restrict__ outp,
                                          const float* __restrict__ addsrc,
                                          int K, float scale, int m0, int n0)
{
    constexpr int MI  = TM / 32;
    constexpr int ASZ = TM * BK;
    constexpr int BSZ = 128 * BK;
    constexpr int RPI = 512 / BK;
    constexpr int NIA = (TM / 4) / RPI;
    constexpr int NIB = 32 / RPI;
    constexpr int NI  = NIA + NIB;
    __shared__ u16 As[2 * ASZ];
    __shared__ u16 Bs[2 * BSZ];
    const int tid = threadIdx.x;
    const int l = tid & 63, w = tid >> 6;
    const int wr = w >> 1, wc = w & 1;
    const int lr = l & 15, lg = l >> 4;

    int srow, sblk;
    if constexpr (BK == 32) { srow = l >> 2; sblk = (l & 3) ^ ((l >> 3) & 3); }
    else                    { srow = l >> 3; sblk = (l & 7) ^ (l >> 3); }
    const u16* gA = A  + (size_t)(m0 + w * (TM / 4) + srow) * K + sblk * 8;
    const u16* gB = Bt + (size_t)(n0 + w * 32 + srow) * K + sblk * 8;
    const size_t rowKi = (size_t)RPI * K;
    u16* const lA0 = As + w * (TM / 4) * BK;
    u16* const lB0 = Bs + w * 32 * BK;

    f32x4 acc[MI][4];
    #pragma unroll
    for (int i = 0; i < MI; i++)
        #pragma unroll
        for (int j = 0; j < 4; j++) acc[i][j] = (f32x4)(0.0f);

    auto stage = [&](int buf, int kb) {
        u16* la = lA0 + buf * ASZ;
        u16* lb = lB0 + buf * BSZ;
        #pragma unroll
        for (int i = 0; i < NIA; i++) gll16(gA + kb + i * rowKi, la + i * 512);
        #pragma unroll
        for (int i = 0; i < NIB; i++) gll16(gB + kb + i * rowKi, lb + i * 512);
    };

    const int nK = K / BK;
    stage(0, 0);
    int cur = 0;
    for (int kt = 0; kt < nK; ++kt) {
        __builtin_amdgcn_sched_barrier(0);
        __builtin_amdgcn_s_barrier();
        __builtin_amdgcn_sched_barrier(0);
        if (kt + 1 < nK) {
            stage(cur ^ 1, (kt + 1) * BK);
            waitv<NI>();
        } else {
            waitv<0>();
        }
        __builtin_amdgcn_s_barrier();
        __builtin_amdgcn_sched_barrier(0);

        const u16* as = As + cur * ASZ;
        const u16* bs = Bs + cur * BSZ;
        #pragma unroll
        for (int ks = 0; ks < BK / 32; ks++) {
            int off;
            if constexpr (BK == 32) off = (lg ^ ((lr >> 1) & 3)) * 8;
            else                    off = ((ks * 4 + lg) ^ (lr & 7)) * 8;
            bf16x8 af[MI], bf[4];
            #pragma unroll
            for (int mi = 0; mi < MI; mi++)
                af[mi] = *(const bf16x8*)(as + (wr * (MI * 16) + mi * 16 + lr) * BK + off);
            #pragma unroll
            for (int ni = 0; ni < 4; ni++)
                bf[ni] = *(const bf16x8*)(bs + (wc * 64 + ni * 16 + lr) * BK + off);
            #pragma unroll
            for (int mi = 0; mi < MI; mi++)
                #pragma unroll
                for (int ni = 0; ni < 4; ni++)
                    acc[mi][ni] = __builtin_amdgcn_mfma_f32_16x16x32_bf16(
                        af[mi], bf[ni], acc[mi][ni], 0, 0, 0);
        }
        cur ^= 1;
    }

    const int r0 = lg * 4;
    #pragma unroll
    for (int mi = 0; mi < MI; mi++) {
        #pragma unroll
        for (int ni = 0; ni < 4; ni++) {
            const int col = n0 + wc * 64 + ni * 16 + lr;
            const float bv = bias[col];
            #pragma unroll
            for (int r = 0; r < 4; r++) {
                const int row = m0 + wr * (MI * 16) + mi * 16 + r0 + r;
                const float v = acc[mi][ni][r] + bv;
                if constexpr (EPI == 0) {
                    const int bb = row >> 11, s = row & 2047;
                    const int hh = col >> 6, hd = col & 63;
                    ((u16*)outp)[(((size_t)(bb * 16 + hh) * 2048) + s) * 64 + hd] = f2bf(v * scale);
                } else if constexpr (EPI == 1 || EPI == 3) {
                    const size_t idx = (size_t)row * 1024 + col;
                    ((float*)outp)[idx] = addsrc[idx] + v;
                } else {
                    ((u16*)outp)[(size_t)row * 4096 + col] = f2bf(gelu7(v));
                }
            }
        }
    }
}

// 1-D grid, bijective XCD swizzle (nwg % 8 == 0), n-fast within an XCD.
template<int EPI, int TM, int BK, int NX>
__global__ __launch_bounds__(256) void gemm_k(const u16* __restrict__ A,
                                              const u16* __restrict__ Bt,
                                              const float* __restrict__ bias,
                                              void* __restrict__ outp,
                                              const float* __restrict__ addsrc,
                                              int K)
{
    const int nwg = gridDim.x;
    const int s = (blockIdx.x & 7) * (nwg >> 3) + (blockIdx.x >> 3);
    gemm_body<EPI, TM, BK>(A, Bt, bias, outp, addsrc, K, 1.0f,
                           (s / NX) * TM, (s % NX) * 128);
}

// MLP1 (TM=64/BK=64, grid 2048): XCD owns 16m x 16n super-tile, walked in
// 4 generations of 16m x 4n (m-fast inner); generation working set ~3MB.
__global__ __launch_bounds__(256) void gemm_mlp1_k(const u16* __restrict__ A,
                                                   const u16* __restrict__ Bt,
                                                   const float* __restrict__ bias,
                                                   void* __restrict__ outp,
                                                   int K)
{
    const int x = blockIdx.x & 7;
    const int idx = blockIdx.x >> 3;          // 0..255
    const int m = (x >> 1) * 16 + (idx & 15);
    const int n = (x & 1) * 16 + (idx >> 6) * 4 + ((idx >> 4) & 3);
    gemm_body<2, 64, 64>(A, Bt, bias, outp, nullptr, K, 1.0f, m * 64, n * 128);
}

// fused QKV (grid 768): XCD owns a disjoint 4-m-panel slice of shared A.
__global__ __launch_bounds__(256) void gemm_qkv_k(const u16* __restrict__ A,
                                                  const u16* __restrict__ WtBase,
                                                  const float* __restrict__ bq,
                                                  const float* __restrict__ bk,
                                                  const float* __restrict__ bv,
                                                  u16* __restrict__ outBase)
{
    const int x = blockIdx.x & 7;
    const int i = blockIdx.x >> 3;            // 0..95
    const int m = x * 4 + (i & 3);            // 0..31
    const int rest = i >> 2;                  // 0..23
    const int z = rest >> 3, n = rest & 7;
    const u16* Bt = WtBase + (size_t)z * 1024 * 1024;
    const float* bias = (z == 0) ? bq : (z == 1) ? bk : bv;
    u16* outp = outBase + (size_t)z * 4096 * 1024;
    const float scale = (z == 0) ? QSCALE : 1.0f;
    gemm_body<0, 128, 32>(A, Bt, bias, outp, nullptr, 1024, scale,
                          m * 128, n * 128);
}

// ---------------------------------------------------------------------------
// MFMA flash attention, swapped-QK^T, no max tracking; KV-TILE = 128 (R16):
// one barrier pair + one counted vmcnt per 128 kv (two 64-kv compute passes
// inside). Wave owns 32 q rows as two 16-row groups sharing every K/V
// fragment read. Grid 512 (2 blocks/CU, LDS 80KB).
// ---------------------------------------------------------------------------
__global__ __launch_bounds__(256) void attn_mfma_k(
    const u16* __restrict__ Qb, const u16* __restrict__ Kb,
    const u16* __restrict__ Vt, u16* __restrict__ Oo)
{
    __shared__ u16 Kl[2][128 * 64];    // [kv][hd]
    __shared__ u16 Vl[2][64 * 128];    // [hd][kv]
    __shared__ u16 Pl[4][32 * 64];     // per-wave P: 32 q rows

    const int tid = threadIdx.x;
    const int l = tid & 63, w = tid >> 6;
    const int lr = l & 15, lg = l >> 4;
    const int bid = blockIdx.x;
    const int bh = (bid & 7) * 4 + ((bid >> 3) >> 4);   // 4 heads per XCD
    const int qblk = (bid >> 3) & 15;
    const size_t base = (size_t)bh * 2048 * 64;
    const size_t vbase = (size_t)bh * 64 * 2048;
    const int q0 = qblk * 128 + w * 32;

    bf16x8 qf[2][2];
    #pragma unroll
    for (int g = 0; g < 2; g++)
        #pragma unroll
        for (int ks = 0; ks < 2; ks++)
            qf[g][ks] = *(const bf16x8*)(Qb + base + (size_t)(q0 + g * 16 + lr) * 64
                                         + ks * 32 + lg * 8);

    bf16x8 onef;
    #pragma unroll
    for (int j = 0; j < 8; j++) onef[j] = (short)0x3F80;

    f32x4 o_[2][4];
    f32x4 ol[2];
    #pragma unroll
    for (int g = 0; g < 2; g++) {
        #pragma unroll
        for (int r = 0; r < 4; r++) ol[g][r] = 0.0f;
        #pragma unroll
        for (int ni = 0; ni < 4; ni++) o_[g][ni] = (f32x4)(0.0f);
    }

    u16* const plw = &Pl[w][0];
    u16* pw_[2][4];
    const u16* pr_[2][2];
    #pragma unroll
    for (int g = 0; g < 2; g++) {
        #pragma unroll
        for (int ni = 0; ni < 4; ni++)
            pw_[g][ni] = plw + (g * 16 + lr) * 64
                       + (((ni * 2 + (lg >> 1)) ^ (lr & 7)) * 8 + (lg & 1) * 4);
        pr_[g][0] = plw + (g * 16 + lr) * 64 + ((lg ^ (lr & 7)) * 8);
        pr_[g][1] = plw + (g * 16 + lr) * 64 + (((4 + lg) ^ (lr & 7)) * 8);
    }

    const u16* gK = Kb + base + (size_t)(w * 32 + (l >> 3)) * 64
                  + (((l & 7) ^ (l >> 3)) * 8);
    u16* const kd = &Kl[0][0] + w * 32 * 64;

    const u16* gVsrc[4];
    #pragma unroll
    for (int i = 0; i < 4; i++) {
        const int vrow = w * 16 + i * 4 + (l >> 4);
        gVsrc[i] = Vt + vbase + (size_t)vrow * 2048
                 + (((l & 15) ^ (i * 4 + (l >> 4))) * 8);
    }
    u16* const vd = &Vl[0][0] + w * 16 * 128;

    auto stageT = [&](int buf, int kv) {
        u16* kdb = kd + buf * 8192;
        u16* vdb = vd + buf * 8192;
        #pragma unroll
        for (int i = 0; i < 4; i++)
            gll16(gK + (size_t)kv * 64 + i * 512, kdb + i * 512);
        #pragma unroll
        for (int i = 0; i < 4; i++)
            gll16(gVsrc[i] + kv, vdb + i * 512);
    };

    stageT(0, 0);
    int cur = 0;
    for (int t = 0; t < 16; ++t) {
        __builtin_amdgcn_sched_barrier(0);
        __builtin_amdgcn_s_barrier();
        __builtin_amdgcn_sched_barrier(0);
        if (t < 15) {
            stageT(cur ^ 1, (t + 1) * 128);
            waitv<8>();
        } else {
            waitv<0>();
        }
        __builtin_amdgcn_s_barrier();
        __builtin_amdgcn_sched_barrier(0);

        #pragma unroll
        for (int s = 0; s < 2; s++) {
            f32x4 s_[2][4];
            #pragma unroll
            for (int g = 0; g < 2; g++)
                #pragma unroll
                for (int ni = 0; ni < 4; ni++) s_[g][ni] = (f32x4)(0.0f);
            __builtin_amdgcn_s_setprio(1);
            #pragma unroll
            for (int ks = 0; ks < 2; ks++)
                #pragma unroll
                for (int ni = 0; ni < 4; ni++) {
                    const int row = ni * 16 + lr;
                    const bf16x8 kf = *(const bf16x8*)(
                        &Kl[cur][(s * 64 + row) * 64 + (((ks * 4 + lg) ^ (row & 7)) * 8)]);
                    s_[0][ni] = __builtin_amdgcn_mfma_f32_16x16x32_bf16(kf, qf[0][ks], s_[0][ni], 0, 0, 0);
                    s_[1][ni] = __builtin_amdgcn_mfma_f32_16x16x32_bf16(kf, qf[1][ks], s_[1][ni], 0, 0, 0);
                }
            __builtin_amdgcn_s_setprio(0);

            #pragma unroll
            for (int g = 0; g < 2; g++)
                #pragma unroll
                for (int ni = 0; ni < 4; ni++) {
                    u32x2 pv;
                    pv[0] = cvtpk(ex2(s_[g][ni][0]), ex2(s_[g][ni][1]));
                    pv[1] = cvtpk(ex2(s_[g][ni][2]), ex2(s_[g][ni][3]));
                    *(u32x2*)pw_[g][ni] = pv;
                }

            __builtin_amdgcn_s_setprio(1);
            #pragma unroll
            for (int ks = 0; ks < 2; ks++) {
                const bf16x8 pf0 = *(const bf16x8*)pr_[0][ks];
                const bf16x8 pf1 = *(const bf16x8*)pr_[1][ks];
                ol[0] = __builtin_amdgcn_mfma_f32_16x16x32_bf16(pf0, onef, ol[0], 0, 0, 0);
                ol[1] = __builtin_amdgcn_mfma_f32_16x16x32_bf16(pf1, onef, ol[1], 0, 0, 0);
                #pragma unroll
                for (int ni = 0; ni < 4; ni++) {
                    const int row = ni * 16 + lr;
                    const int chunk = s * 8 + ks * 4 + lg;
                    const bf16x8 vf = *(const bf16x8*)(
                        &Vl[cur][row * 128 + ((chunk ^ (row & 15)) * 8)]);
                    o_[0][ni] = __builtin_amdgcn_mfma_f32_16x16x32_bf16(pf0, vf, o_[0][ni], 0, 0, 0);
                    o_[1][ni] = __builtin_amdgcn_mfma_f32_16x16x32_bf16(pf1, vf, o_[1][ni], 0, 0, 0);
                }
            }
            __builtin_amdgcn_s_setprio(0);
        }
        cur ^= 1;
    }

    const int bb = bh >> 4, hh = bh & 15;
    #pragma unroll
    for (int g = 0; g < 2; g++)
        #pragma unroll
        for (int r = 0; r < 4; r++) {
            const float inv = 1.0f / ol[g][r];
            const int qrow = q0 + g * 16 + lg * 4 + r;
            u16* dst = Oo + ((size_t)(bb * 2048 + qrow)) * 1024 + hh * 64;
            #pragma unroll
            for (int ni = 0; ni < 4; ni++)
                dst[ni * 16 + lr] = f2bf(o_[g][ni][r] * inv);
        }
}

// ---------------------------------------------------------------------------
extern "C" void kernel_launch(void* const* d_in, const int* in_sizes, int n_in,
                              void* d_out, int out_size, void* d_ws, size_t ws_size,
                              hipStream_t stream)
{
    const float* x     = (const float*)d_in[0];
    const float* ln1_g = (const float*)d_in[1];
    const float* ln1_b = (const float*)d_in[2];
    const float* wq    = (const float*)d_in[3];
    const float* bq    = (const float*)d_in[4];
    const float* wk    = (const float*)d_in[5];
    const float* bk    = (const float*)d_in[6];
    const float* wv    = (const float*)d_in[7];
    const float* bv    = (const float*)d_in[8];
    const float* wo    = (const float*)d_in[9];
    const float* bo    = (const float*)d_in[10];
    const float* ln2_g = (const float*)d_in[11];
    const float* ln2_b = (const float*)d_in[12];
    const float* w1    = (const float*)d_in[13];
    const float* b1    = (const float*)d_in[14];
    const float* w2    = (const float*)d_in[15];
    const float* b2    = (const float*)d_in[16];

    char* ws = (char*)d_ws;
    size_t off = 0;
    auto alloc = [&](size_t bytes) {
        char* p = ws + off;
        off += (bytes + 255) & ~(size_t)255;
        return p;
    };
    // NOTE: wtq/wtk/wtv/wto must stay contiguous (tcvt4_k / gemm_qkv_k index
    // by z), as must qb/kb/vb. Each is an exact multiple of 256B.
    u16* wtq = (u16*)alloc((size_t)1024 * 1024 * 2);
    u16* wtk = (u16*)alloc((size_t)1024 * 1024 * 2);
    u16* wtv = (u16*)alloc((size_t)1024 * 1024 * 2);
    u16* wto = (u16*)alloc((size_t)1024 * 1024 * 2);
    u16* wt1 = (u16*)alloc((size_t)4096 * 1024 * 2);  // [MLP][D]
    u16* wt2 = (u16*)alloc((size_t)1024 * 4096 * 2);  // [D][MLP]
    u16* h1  = (u16*)alloc((size_t)4096 * 1024 * 2);
    u16* qb  = (u16*)alloc((size_t)4096 * 1024 * 2);  // [B*H][S][HD]
    u16* kb  = (u16*)alloc((size_t)4096 * 1024 * 2);
    u16* vb  = (u16*)alloc((size_t)4096 * 1024 * 2);
    u16* ao  = (u16*)alloc((size_t)4096 * 1024 * 2);  // [B,S,D]
    float* x2 = (float*)alloc((size_t)4096 * 1024 * 4);
    u16* h2  = (u16*)alloc((size_t)4096 * 1024 * 2);
    u16* mid = (u16*)alloc((size_t)4096 * 4096 * 2);
    // V^T [32][64][2048] aliases `mid` (mid is first written AFTER attention).
    u16* vt  = mid;
    (void)ws_size;
    (void)wtk; (void)wtv;

    const dim3 tb(32, 8);
    tcvt4_k<<<dim3(32, 32, 4), tb, 0, stream>>>(wq, wk, wv, wo, wtq);
    tcvt_k<<<dim3(128, 32), tb, 0, stream>>>(w1, wt1, 1024, 4096);
    tcvt_k<<<dim3(32, 128), tb, 0, stream>>>(w2, wt2, 4096, 1024);

    ln_k<<<1024, 256, 0, stream>>>(x, ln1_g, ln1_b, h1);

    gemm_qkv_k<<<768, 256, 0, stream>>>(h1, wtq, bq, bk, bv, qb);

    vtr_k<<<dim3(32, 32), 256, 0, stream>>>(vb, vt);
    attn_mfma_k<<<512, 256, 0, stream>>>(qb, kb, vt, ao);

    gemm_k<1, 64, 64, 8><<<512, 256, 0, stream>>>(ao, wto, bo, x2, x, 1024);

    ln_k<<<1024, 256, 0, stream>>>(x2, ln2_g, ln2_b, h2);

    gemm_mlp1_k<<<2048, 256, 0, stream>>>(h2, wt1, b1, mid, 1024);
    gemm_k<3, 64, 64, 8><<<512, 256, 0, stream>>>(mid, wt2, b2, (float*)d_out, x2, 4096);
}